// Round 4
// baseline (315.205 us; speedup 1.0000x reference)
//
#include <hip/hip_runtime.h>
#include <cstdint>
#include <cstddef>

#define BN_EPS 1e-5f

typedef short bf16x8 __attribute__((ext_vector_type(8)));
typedef float f32x4  __attribute__((ext_vector_type(4)));
typedef unsigned short u16x8 __attribute__((ext_vector_type(8)));

__device__ __forceinline__ uint16_t f2bf_rte(float f) {
  uint32_t u = __float_as_uint(f);
  uint32_t r = u + 0x7fffu + ((u >> 16) & 1u);
  return (uint16_t)(r >> 16);
}
__device__ __forceinline__ float bf2f(uint16_t h) {
  return __uint_as_float(((uint32_t)h) << 16);
}
__device__ __forceinline__ void split_bf(float v, uint16_t& hi, uint16_t& lo) {
  hi = f2bf_rte(v);
  lo = f2bf_rte(v - bf2f(hi));
}

// ---------------- CSR build over dst ----------------
__global__ void zero_i32_k(int* p, int n) {
  int i = blockIdx.x * blockDim.x + threadIdx.x;
  if (i < n) p[i] = 0;
}

__global__ void hist_k(const int* __restrict__ dst, int* __restrict__ cnt, int E) {
  int e = blockIdx.x * blockDim.x + threadIdx.x;
  if (e < E) atomicAdd(&cnt[dst[e]], 1);
}

__global__ __launch_bounds__(1024) void scan_k(const int* __restrict__ cnt,
                                               int* __restrict__ offsets,
                                               int* __restrict__ cursor,
                                               int N, int total) {
  __shared__ int part[1024];
  int t = threadIdx.x;
  int a0 = cnt[4*t+0], a1 = cnt[4*t+1], a2 = cnt[4*t+2], a3 = cnt[4*t+3];
  part[t] = a0 + a1 + a2 + a3;
  __syncthreads();
  for (int off = 1; off < 1024; off <<= 1) {
    int v = (t >= off) ? part[t - off] : 0;
    __syncthreads();
    part[t] += v;
    __syncthreads();
  }
  int excl = (t == 0) ? 0 : part[t-1];
  int o0 = excl, o1 = o0 + a0, o2 = o1 + a1, o3 = o2 + a2;
  offsets[4*t+0] = o0; offsets[4*t+1] = o1; offsets[4*t+2] = o2; offsets[4*t+3] = o3;
  cursor [4*t+0] = o0; cursor [4*t+1] = o1; cursor [4*t+2] = o2; cursor [4*t+3] = o3;
  if (t == 0) offsets[N] = total;
}

__global__ void scatter_k(const int* __restrict__ dst, int* __restrict__ cursor,
                          int* __restrict__ csr, int E) {
  int e = blockIdx.x * blockDim.x + threadIdx.x;
  if (e < E) {
    int d = dst[e];
    int pos = atomicAdd(&cursor[d], 1);
    csr[pos] = e;
  }
}

// ---------------- W2'^T build: [cout][Kpad] bf16 hi/lo; k 0..31 W2, 32 b2, 33 root ----------------
__global__ void build_W2pT_k(const float* __restrict__ W2, const float* __restrict__ b2,
                             const float* __restrict__ root,
                             uint16_t* __restrict__ Bhi, uint16_t* __restrict__ Blo,
                             int cin, int cout, int Kpad) {
  int idx = blockIdx.x * blockDim.x + threadIdx.x;
  int total = cout * Kpad;
  if (idx >= total) return;
  int o  = idx / Kpad;
  int ki = idx - o * Kpad;
  float v = 0.f;
  if (ki < 34 * cin) {
    int k = ki / cin;
    int i = ki - k * cin;
    if (k < 32)       v = W2[(size_t)k * cin * cout + (size_t)i * cout + o];
    else if (k == 32) v = b2[(size_t)i * cout + o];
    else              v = root[(size_t)i * cout + o];
  }
  uint16_t hi, lo;
  split_bf(v, hi, lo);
  Bhi[idx] = hi;
  Blo[idx] = lo;
}

// ---------------- S build, vectorized (CIN in {64,128}), fused edge-MLP z ----------------
template<int CIN>
__global__ __launch_bounds__(256) void build_S_vec_k(const float* __restrict__ h,
                                                     const float* __restrict__ ea,
                                                     const float* __restrict__ W1,
                                                     const float* __restrict__ b1,
                                                     const int* __restrict__ src,
                                                     const int* __restrict__ csr,
                                                     const int* __restrict__ offsets,
                                                     uint16_t* __restrict__ Shi,
                                                     uint16_t* __restrict__ Slo,
                                                     int Kpad) {
  constexpr int CH = 8;
  constexpr int K1 = 33 * CIN;
  constexpr int NCH = K1 / 8;
  constexpr int NP = (NCH + 255) / 256;
  __shared__ float hs[CH][CIN];
  __shared__ float zs[CH][33];
  __shared__ int   es[CH];
  const int n = blockIdx.x;
  const int tid = threadIdx.x;
  const int base = offsets[n];
  const int deg  = offsets[n+1] - base;
  const float scale = 1.f / fmaxf((float)deg, 1.f);
  float acc[NP][8];
#pragma unroll
  for (int p = 0; p < NP; p++)
#pragma unroll
    for (int j = 0; j < 8; j++) acc[p][j] = 0.f;

  for (int c0 = 0; c0 < deg; c0 += CH) {
    const int cc = min(CH, deg - c0);
    if (tid < cc) es[tid] = csr[base + c0 + tid];
    __syncthreads();
    for (int idx = tid; idx < cc * CIN; idx += 256) {
      int slot = idx / CIN, i = idx - slot * CIN;
      hs[slot][i] = h[(size_t)src[es[slot]] * CIN + i];
    }
    for (int idx = tid; idx < cc * 33; idx += 256) {
      int slot = idx / 33, k = idx - slot * 33;
      float v;
      if (k == 32) v = 1.f;
      else {
        int e = es[slot];
        v = fmaxf(ea[e*3+0] * W1[k] + ea[e*3+1] * W1[32 + k] + ea[e*3+2] * W1[64 + k] + b1[k], 0.f);
      }
      zs[slot][k] = v;
    }
    __syncthreads();
#pragma unroll
    for (int p = 0; p < NP; p++) {
      int ch = p * 256 + tid;
      if (ch < NCH) {
        int ki0 = ch * 8;
        int k  = ki0 / CIN;
        int i0 = ki0 & (CIN - 1);
        for (int c = 0; c < cc; c++) {
          float zv = zs[c][k];
          float4 h0 = *(const float4*)&hs[c][i0];
          float4 h1 = *(const float4*)&hs[c][i0 + 4];
          acc[p][0] += zv * h0.x; acc[p][1] += zv * h0.y;
          acc[p][2] += zv * h0.z; acc[p][3] += zv * h0.w;
          acc[p][4] += zv * h1.x; acc[p][5] += zv * h1.y;
          acc[p][6] += zv * h1.z; acc[p][7] += zv * h1.w;
        }
      }
    }
    __syncthreads();
  }
  const size_t rowb = (size_t)n * Kpad;
#pragma unroll
  for (int p = 0; p < NP; p++) {
    int ch = p * 256 + tid;
    if (ch < NCH) {
      u16x8 hv, lv;
#pragma unroll
      for (int j = 0; j < 8; j++) {
        uint16_t hi, lo;
        split_bf(acc[p][j] * scale, hi, lo);
        hv[j] = hi; lv[j] = lo;
      }
      *(u16x8*)(Shi + rowb + ch * 8) = hv;
      *(u16x8*)(Slo + rowb + ch * 8) = lv;
    }
  }
  for (int c = tid; c < CIN / 8; c += 256) {
    int i0 = c * 8;
    float4 a = *(const float4*)&h[(size_t)n * CIN + i0];
    float4 b = *(const float4*)&h[(size_t)n * CIN + i0 + 4];
    float vals[8] = {a.x, a.y, a.z, a.w, b.x, b.y, b.z, b.w};
    u16x8 hv, lv;
#pragma unroll
    for (int j = 0; j < 8; j++) {
      uint16_t hi, lo;
      split_bf(vals[j], hi, lo);
      hv[j] = hi; lv[j] = lo;
    }
    *(u16x8*)(Shi + rowb + K1 + i0) = hv;
    *(u16x8*)(Slo + rowb + K1 + i0) = lv;
  }
  for (int ki = 34 * CIN + tid; ki < Kpad; ki += 256) {
    Shi[rowb + ki] = 0;
    Slo[rowb + ki] = 0;
  }
}

// scalar variant for CIN=5 (layer 1)
__global__ __launch_bounds__(256) void build_S5_k(const float* __restrict__ h,
                                                  const float* __restrict__ ea,
                                                  const float* __restrict__ W1,
                                                  const float* __restrict__ b1,
                                                  const int* __restrict__ src,
                                                  const int* __restrict__ csr,
                                                  const int* __restrict__ offsets,
                                                  uint16_t* __restrict__ Shi,
                                                  uint16_t* __restrict__ Slo,
                                                  int Kpad) {
  constexpr int CIN = 5, CH = 8;
  constexpr int K1 = 33 * CIN;   // 165
  constexpr int KT = 34 * CIN;   // 170
  __shared__ float hs[CH][CIN];
  __shared__ float zs[CH][33];
  __shared__ int   es[CH];
  const int n = blockIdx.x;
  const int tid = threadIdx.x;
  const int base = offsets[n];
  const int deg  = offsets[n+1] - base;
  const float scale = 1.f / fmaxf((float)deg, 1.f);
  float acc = 0.f;

  for (int c0 = 0; c0 < deg; c0 += CH) {
    const int cc = min(CH, deg - c0);
    if (tid < cc) es[tid] = csr[base + c0 + tid];
    __syncthreads();
    for (int idx = tid; idx < cc * CIN; idx += 256) {
      int slot = idx / CIN, i = idx - slot * CIN;
      hs[slot][i] = h[(size_t)src[es[slot]] * CIN + i];
    }
    for (int idx = tid; idx < cc * 33; idx += 256) {
      int slot = idx / 33, k = idx - slot * 33;
      float v;
      if (k == 32) v = 1.f;
      else {
        int e = es[slot];
        v = fmaxf(ea[e*3+0] * W1[k] + ea[e*3+1] * W1[32 + k] + ea[e*3+2] * W1[64 + k] + b1[k], 0.f);
      }
      zs[slot][k] = v;
    }
    __syncthreads();
    if (tid < K1) {
      int k = tid / CIN, i = tid - (tid / CIN) * CIN;
      float a = acc;
      for (int c = 0; c < cc; c++) a += zs[c][k] * hs[c][i];
      acc = a;
    }
    __syncthreads();
  }
  const size_t rowb = (size_t)n * Kpad;
  if (tid < K1) {
    uint16_t hi, lo;
    split_bf(acc * scale, hi, lo);
    Shi[rowb + tid] = hi;
    Slo[rowb + tid] = lo;
  }
  if (tid < CIN) {
    uint16_t hi, lo;
    split_bf(h[(size_t)n * CIN + tid], hi, lo);
    Shi[rowb + K1 + tid] = hi;
    Slo[rowb + K1 + tid] = lo;
  }
  for (int ki = KT + tid; ki < Kpad; ki += 256) {
    Shi[rowb + ki] = 0;
    Slo[rowb + ki] = 0;
  }
}

// ---------------- split-K MFMA bf16x3 GEMM: 128x128 tile, 4 waves x 64x64 ----------------
// XOR-swizzled LDS (octet ^ (row&7)): all ds ops 16B-aligned b128, <=2-way per phase.
__global__ __launch_bounds__(256, 2) void mfma_gemm_sk2_k(const uint16_t* __restrict__ Ahi,
                                                          const uint16_t* __restrict__ Alo,
                                                          const uint16_t* __restrict__ Bhi,
                                                          const uint16_t* __restrict__ Blo,
                                                          float* __restrict__ Cpart,
                                                          int Kpad, int Ncol, int M,
                                                          int iters, int SK) {
  __shared__ uint16_t As[2][128][64];   // 32 KB
  __shared__ uint16_t Bs[2][128][64];   // 32 KB
  const int m0 = blockIdx.x * 128, n0 = blockIdx.y * 128;
  const int z  = blockIdx.z;
  const int ibase = iters / SK, irem = iters % SK;
  const int i0    = z * ibase + min(z, irem);
  const int niter = ibase + (z < irem ? 1 : 0);
  const int tid  = threadIdx.x;
  const int lane = tid & 63;
  const int wave = tid >> 6;
  const int wm = wave & 1, wn = wave >> 1;   // 2x2 waves, each 64x64
  const int q  = lane >> 4;
  const int mr = lane & 15;

  f32x4 acc[4][4];
#pragma unroll
  for (int a = 0; a < 4; a++)
#pragma unroll
    for (int b = 0; b < 4; b++) acc[a][b] = (f32x4)0.f;

  for (int it = 0; it < niter; it++) {
    const int k0 = (i0 + it) * 64;
    // stage 64 KB: 4096 16B-chunks, 16 per thread
#pragma unroll
    for (int i = 0; i < 16; i++) {
      int chunk = i * 256 + tid;
      int coct = chunk & 7;
      int row  = (chunk >> 3) & 127;
      int plane = (chunk >> 10) & 1;
      int arr   = chunk >> 11;
      const uint16_t* gsrc = arr ? (plane ? Blo : Bhi) : (plane ? Alo : Ahi);
      int grow = (arr ? n0 : m0) + row;
      uint4 v = {0u, 0u, 0u, 0u};
      if (arr == 0 || grow < Ncol)
        v = *(const uint4*)(gsrc + (size_t)grow * Kpad + k0 + coct * 8);
      int soct = coct ^ (row & 7);
      uint16_t* ldst = arr ? &Bs[plane][row][soct * 8] : &As[plane][row][soct * 8];
      *(uint4*)ldst = v;
    }
    __syncthreads();
#pragma unroll
    for (int ks = 0; ks < 2; ks++) {
      const int oct = (ks * 4 + q) ^ (mr & 7);
      bf16x8 bh[4], bl[4];
#pragma unroll
      for (int f = 0; f < 4; f++) {
        int row = wn * 64 + f * 16 + mr;
        bh[f] = *(const bf16x8*)&Bs[0][row][oct * 8];
        bl[f] = *(const bf16x8*)&Bs[1][row][oct * 8];
      }
#pragma unroll
      for (int fm = 0; fm < 4; fm++) {
        int row = wm * 64 + fm * 16 + mr;
        bf16x8 ah = *(const bf16x8*)&As[0][row][oct * 8];
        bf16x8 al = *(const bf16x8*)&As[1][row][oct * 8];
#pragma unroll
        for (int fn = 0; fn < 4; fn++) {
          acc[fm][fn] = __builtin_amdgcn_mfma_f32_16x16x32_bf16(ah, bh[fn], acc[fm][fn], 0, 0, 0);
          acc[fm][fn] = __builtin_amdgcn_mfma_f32_16x16x32_bf16(ah, bl[fn], acc[fm][fn], 0, 0, 0);
          acc[fm][fn] = __builtin_amdgcn_mfma_f32_16x16x32_bf16(al, bh[fn], acc[fm][fn], 0, 0, 0);
        }
      }
    }
    __syncthreads();
  }

  // C/D layout: row = q*4 + reg, col = mr (verified)
  float* Cz = Cpart + (size_t)z * M * Ncol;
#pragma unroll
  for (int fm = 0; fm < 4; fm++) {
#pragma unroll
    for (int reg = 0; reg < 4; reg++) {
      int row = m0 + wm * 64 + fm * 16 + q * 4 + reg;
#pragma unroll
      for (int fn = 0; fn < 4; fn++) {
        int col = n0 + wn * 64 + fn * 16 + mr;
        if (col < Ncol)
          Cz[(size_t)row * Ncol + col] = acc[fm][fn][reg];
      }
    }
  }
}

// ---------------- split-K reduce + bias + BN + ReLU epilogue ----------------
__global__ void epilogue_k(const float* __restrict__ Cpart, int SK, size_t plane4,
                           int Ncol,
                           const float* __restrict__ bias, const float* __restrict__ bg,
                           const float* __restrict__ bb, const float* __restrict__ bnm,
                           const float* __restrict__ bnv,
                           float* __restrict__ C, int total4) {
  int i = blockIdx.x * blockDim.x + threadIdx.x;
  if (i >= total4) return;
  float4 v = {0.f, 0.f, 0.f, 0.f};
  for (int z = 0; z < SK; z++) {
    float4 p = *((const float4*)Cpart + (size_t)z * plane4 + i);
    v.x += p.x; v.y += p.y; v.z += p.z; v.w += p.w;
  }
  int col0 = (i * 4) % Ncol;
  float o[4] = {v.x, v.y, v.z, v.w};
#pragma unroll
  for (int j = 0; j < 4; j++) {
    int c = col0 + j;
    float s = bg[c] * rsqrtf(bnv[c] + BN_EPS);
    float val = (o[j] + bias[c] - bnm[c]) * s + bb[c];
    o[j] = fmaxf(val, 0.f);
  }
  float4 r = {o[0], o[1], o[2], o[3]};
  *((float4*)C + i) = r;
}

// ---------------- fused pool (mean over sorted batch_seg) + final MLP + LeakyReLU ----------------
__global__ __launch_bounds__(256) void pool_final_k(const float* __restrict__ h,
                                                    const int* __restrict__ seg,
                                                    const float* __restrict__ W,
                                                    const float* __restrict__ b,
                                                    float* __restrict__ out,
                                                    int N, int T) {
  __shared__ float pooled[256];
  const int g = blockIdx.x, tid = threadIdx.x;
  int lo = 0, hi = N;
  while (lo < hi) { int mid = (lo + hi) >> 1; if (seg[mid] < g) lo = mid + 1; else hi = mid; }
  int lo2 = lo, hi2 = N;
  while (lo2 < hi2) { int mid = (lo2 + hi2) >> 1; if (seg[mid] < g + 1) lo2 = mid + 1; else hi2 = mid; }
  const int cnt = lo2 - lo;
  const float inv = 1.f / fmaxf((float)cnt, 1.f);
  float s = 0.f;
  for (int n = lo; n < lo2; n++) s += h[(size_t)n * 256 + tid];
  pooled[tid] = s * inv;
  __syncthreads();
  if (tid < T) {
    float acc = b[tid];
    for (int o = 0; o < 256; o++) acc += pooled[o] * W[(size_t)o * T + tid];
    out[(size_t)g * T + tid] = (acc > 0.f) ? acc : 0.1f * acc;
  }
}

// ---------------- host orchestration ----------------
extern "C" void kernel_launch(void* const* d_in, const int* in_sizes, int n_in,
                              void* d_out, int out_size, void* d_ws, size_t ws_size,
                              hipStream_t stream) {
  const float* x   = (const float*)d_in[0];
  const int*   ei  = (const int*)d_in[1];
  const float* ea  = (const float*)d_in[2];
  const int*   seg = (const int*)d_in[3];

  const int N = in_sizes[0] / 5;       // 4096
  const int E = in_sizes[2] / 3;       // 16384
  const int T = in_sizes[35];          // 100
  const int G = out_size / T;          // 128
  const int* src = ei;
  const int* dst = ei + E;

  const float *W1[3], *b1[3], *W2[3], *b2[3], *root[3], *bias[3];
  const float *bng[3], *bnb[3], *bnm[3], *bnv[3];
  for (int l = 0; l < 3; l++) {
    int base = 4 + l * 10;
    W1[l]   = (const float*)d_in[base + 0];
    b1[l]   = (const float*)d_in[base + 1];
    W2[l]   = (const float*)d_in[base + 2];
    b2[l]   = (const float*)d_in[base + 3];
    root[l] = (const float*)d_in[base + 4];
    bias[l] = (const float*)d_in[base + 5];
    bng[l]  = (const float*)d_in[base + 6];
    bnb[l]  = (const float*)d_in[base + 7];
    bnm[l]  = (const float*)d_in[base + 8];
    bnv[l]  = (const float*)d_in[base + 9];
  }
  const float* mlpW = (const float*)d_in[34];
  const float* mlpb = (const float*)d_in[35];

  char* p = (char*)d_ws;
  auto carve = [&](size_t bytes) -> char* {
    char* r = p;
    p += (bytes + 255) & ~(size_t)255;
    return r;
  };
  const int KPADMAX = 4352;
  int*      cnt     = (int*)carve((size_t)N * 4);
  int*      offsets = (int*)carve((size_t)(N + 1) * 4);
  int*      cursor  = (int*)carve((size_t)N * 4);
  int*      csr     = (int*)carve((size_t)E * 4);
  uint16_t* Whi     = (uint16_t*)carve((size_t)256 * KPADMAX * 2);
  uint16_t* Wlo     = (uint16_t*)carve((size_t)256 * KPADMAX * 2);
  uint16_t* Shi     = (uint16_t*)carve((size_t)N * KPADMAX * 2);
  uint16_t* Slo     = (uint16_t*)carve((size_t)N * KPADMAX * 2);
  float*    Cpart   = (float*)carve((size_t)16 * N * 128 * 4);  // 33.55 MB (=8*N*256*4)
  float*    hA      = (float*)carve((size_t)N * 256 * 4);
  float*    hB      = (float*)carve((size_t)N * 128 * 4);

  // CSR over dst
  zero_i32_k<<<(N + 255) / 256, 256, 0, stream>>>(cnt, N);
  hist_k<<<(E + 255) / 256, 256, 0, stream>>>(dst, cnt, E);
  scan_k<<<1, 1024, 0, stream>>>(cnt, offsets, cursor, N, E);
  scatter_k<<<(E + 255) / 256, 256, 0, stream>>>(dst, cursor, csr, E);

  const int cins[3]  = {5, 64, 128};
  const int couts[3] = {64, 128, 256};
  const int kpads[3] = {192, 2176, 4352};
  const int sks[3]   = {3, 16, 8};
  const float* hin = x;
  float* houts[3] = {hA, hB, hA};

  for (int l = 0; l < 3; l++) {
    int cin = cins[l], cout = couts[l], Kpad = kpads[l], SK = sks[l];
    int iters = Kpad / 64;
    build_W2pT_k<<<(cout * Kpad + 255) / 256, 256, 0, stream>>>(W2[l], b2[l], root[l],
                                                                Whi, Wlo, cin, cout, Kpad);
    if (cin == 5)
      build_S5_k<<<N, 256, 0, stream>>>(hin, ea, W1[l], b1[l], src, csr, offsets, Shi, Slo, Kpad);
    else if (cin == 64)
      build_S_vec_k<64><<<N, 256, 0, stream>>>(hin, ea, W1[l], b1[l], src, csr, offsets, Shi, Slo, Kpad);
    else
      build_S_vec_k<128><<<N, 256, 0, stream>>>(hin, ea, W1[l], b1[l], src, csr, offsets, Shi, Slo, Kpad);
    dim3 grid(N / 128, (cout + 127) / 128, SK);
    mfma_gemm_sk2_k<<<grid, 256, 0, stream>>>(Shi, Slo, Whi, Wlo, Cpart, Kpad, cout, N, iters, SK);
    int total4 = N * cout / 4;
    epilogue_k<<<(total4 + 255) / 256, 256, 0, stream>>>(Cpart, SK, (size_t)N * cout / 4, cout,
                                                         bias[l], bng[l], bnb[l], bnm[l], bnv[l],
                                                         houts[l], total4);
    hin = houts[l];
  }

  pool_final_k<<<G, 256, 0, stream>>>(hA, seg, mlpW, mlpb, (float*)d_out, N, T);
}

// Round 5
// 311.306 us; speedup vs baseline: 1.0125x; 1.0125x over previous
//
#include <hip/hip_runtime.h>
#include <cstdint>
#include <cstddef>

#define BN_EPS 1e-5f

typedef short bf16x8 __attribute__((ext_vector_type(8)));
typedef float f32x4  __attribute__((ext_vector_type(4)));
typedef unsigned short u16x8 __attribute__((ext_vector_type(8)));

__device__ __forceinline__ uint16_t f2bf_rte(float f) {
  uint32_t u = __float_as_uint(f);
  uint32_t r = u + 0x7fffu + ((u >> 16) & 1u);
  return (uint16_t)(r >> 16);
}
__device__ __forceinline__ float bf2f(uint16_t h) {
  return __uint_as_float(((uint32_t)h) << 16);
}
__device__ __forceinline__ void split_bf(float v, uint16_t& hi, uint16_t& lo) {
  hi = f2bf_rte(v);
  lo = f2bf_rte(v - bf2f(hi));
}

// ---------------- CSR build over dst (cnt zeroed by the big memset) ----------------
__global__ void hist_k(const int* __restrict__ dst, int* __restrict__ cnt, int E) {
  int e = blockIdx.x * blockDim.x + threadIdx.x;
  if (e < E) atomicAdd(&cnt[dst[e]], 1);
}

__global__ __launch_bounds__(1024) void scan_k(const int* __restrict__ cnt,
                                               int* __restrict__ offsets,
                                               int* __restrict__ cursor,
                                               int N, int total) {
  __shared__ int part[1024];
  int t = threadIdx.x;
  int a0 = cnt[4*t+0], a1 = cnt[4*t+1], a2 = cnt[4*t+2], a3 = cnt[4*t+3];
  part[t] = a0 + a1 + a2 + a3;
  __syncthreads();
  for (int off = 1; off < 1024; off <<= 1) {
    int v = (t >= off) ? part[t - off] : 0;
    __syncthreads();
    part[t] += v;
    __syncthreads();
  }
  int excl = (t == 0) ? 0 : part[t-1];
  int o0 = excl, o1 = o0 + a0, o2 = o1 + a1, o3 = o2 + a2;
  offsets[4*t+0] = o0; offsets[4*t+1] = o1; offsets[4*t+2] = o2; offsets[4*t+3] = o3;
  cursor [4*t+0] = o0; cursor [4*t+1] = o1; cursor [4*t+2] = o2; cursor [4*t+3] = o3;
  if (t == 0) offsets[N] = total;
}

__global__ void scatter_k(const int* __restrict__ dst, int* __restrict__ cursor,
                          int* __restrict__ csr, int E) {
  int e = blockIdx.x * blockDim.x + threadIdx.x;
  if (e < E) {
    int d = dst[e];
    int pos = atomicAdd(&cursor[d], 1);
    csr[pos] = e;
  }
}

// ---------------- fused W2'^T build for all 3 layers ----------------
// layout per layer: [cout][Kpad] bf16 hi/lo; k-group 0..31 from W2, 32 = b2, 33 = root
__device__ __forceinline__ void w2pt_one(int idx, const float* W2, const float* b2,
                                         const float* root, uint16_t* Bhi, uint16_t* Blo,
                                         int cin, int cout, int Kpad) {
  int o  = idx / Kpad;
  int ki = idx - o * Kpad;
  float v = 0.f;
  if (ki < 34 * cin) {
    int k = ki / cin;
    int i = ki - k * cin;
    if (k < 32)       v = W2[(size_t)k * cin * cout + (size_t)i * cout + o];
    else if (k == 32) v = b2[(size_t)i * cout + o];
    else              v = root[(size_t)i * cout + o];
  }
  uint16_t hi, lo;
  split_bf(v, hi, lo);
  Bhi[idx] = hi;
  Blo[idx] = lo;
}

__global__ void build_W2pT_all_k(const float* W2a, const float* b2a, const float* roota,
                                 uint16_t* Bhia, uint16_t* Bloa,
                                 const float* W2b, const float* b2b, const float* rootb,
                                 uint16_t* Bhib, uint16_t* Blob,
                                 const float* W2c, const float* b2c, const float* rootc,
                                 uint16_t* Bhic, uint16_t* Bloc) {
  const int T1 = 64 * 192, T2 = 128 * 2176, T3 = 256 * 4352;
  int idx = blockIdx.x * blockDim.x + threadIdx.x;
  if (idx < T1) {
    w2pt_one(idx, W2a, b2a, roota, Bhia, Bloa, 5, 64, 192);
  } else if (idx < T1 + T2) {
    w2pt_one(idx - T1, W2b, b2b, rootb, Bhib, Blob, 64, 128, 2176);
  } else if (idx < T1 + T2 + T3) {
    w2pt_one(idx - T1 - T2, W2c, b2c, rootc, Bhic, Bloc, 128, 256, 4352);
  }
}

// ---------------- S build, vectorized (CIN in {64,128}) ----------------
// Input h is RAW previous-layer GEMM output; we apply fused bias+BN+ReLU affine here.
// S[n, k*cin+i] = (1/deg) * sum_{e: dst==n} z[e,k]*heff[src[e],i]  (k<33, z[.,32]=1)
// rows [33*cin, 34*cin) = heff[n,:]
template<int CIN>
__global__ __launch_bounds__(256) void build_S_vec_k(const float* __restrict__ Craw,
                                                     const float* __restrict__ pbias,
                                                     const float* __restrict__ pg,
                                                     const float* __restrict__ pb,
                                                     const float* __restrict__ pm,
                                                     const float* __restrict__ pv,
                                                     const float* __restrict__ ea,
                                                     const float* __restrict__ W1,
                                                     const float* __restrict__ b1,
                                                     const int* __restrict__ src,
                                                     const int* __restrict__ csr,
                                                     const int* __restrict__ offsets,
                                                     uint16_t* __restrict__ Shi,
                                                     uint16_t* __restrict__ Slo,
                                                     int Kpad) {
  constexpr int CH = 8;
  constexpr int K1 = 33 * CIN;
  constexpr int NCH = K1 / 8;
  constexpr int NP = (NCH + 255) / 256;
  __shared__ float hs[CH][CIN];
  __shared__ float zs[CH][33];
  __shared__ int   es[CH];
  __shared__ float sA[CIN], tA[CIN];
  const int n = blockIdx.x;
  const int tid = threadIdx.x;
  if (tid < CIN) {
    float s = pg[tid] * rsqrtf(pv[tid] + BN_EPS);
    sA[tid] = s;
    tA[tid] = (pbias[tid] - pm[tid]) * s + pb[tid];
  }
  const int base = offsets[n];
  const int deg  = offsets[n+1] - base;
  const float scale = 1.f / fmaxf((float)deg, 1.f);
  float acc[NP][8];
#pragma unroll
  for (int p = 0; p < NP; p++)
#pragma unroll
    for (int j = 0; j < 8; j++) acc[p][j] = 0.f;

  for (int c0 = 0; c0 < deg; c0 += CH) {
    const int cc = min(CH, deg - c0);
    if (tid < cc) es[tid] = csr[base + c0 + tid];
    __syncthreads();
    for (int idx = tid; idx < cc * CIN; idx += 256) {
      int slot = idx / CIN, i = idx - slot * CIN;
      float raw = Craw[(size_t)src[es[slot]] * CIN + i];
      hs[slot][i] = fmaxf(raw * sA[i] + tA[i], 0.f);
    }
    for (int idx = tid; idx < cc * 33; idx += 256) {
      int slot = idx / 33, k = idx - slot * 33;
      float v;
      if (k == 32) v = 1.f;
      else {
        int e = es[slot];
        v = fmaxf(ea[e*3+0] * W1[k] + ea[e*3+1] * W1[32 + k] + ea[e*3+2] * W1[64 + k] + b1[k], 0.f);
      }
      zs[slot][k] = v;
    }
    __syncthreads();
#pragma unroll
    for (int p = 0; p < NP; p++) {
      int ch = p * 256 + tid;
      if (ch < NCH) {
        int ki0 = ch * 8;
        int k  = ki0 / CIN;
        int i0 = ki0 & (CIN - 1);
        for (int c = 0; c < cc; c++) {
          float zv = zs[c][k];
          float4 h0 = *(const float4*)&hs[c][i0];
          float4 h1 = *(const float4*)&hs[c][i0 + 4];
          acc[p][0] += zv * h0.x; acc[p][1] += zv * h0.y;
          acc[p][2] += zv * h0.z; acc[p][3] += zv * h0.w;
          acc[p][4] += zv * h1.x; acc[p][5] += zv * h1.y;
          acc[p][6] += zv * h1.z; acc[p][7] += zv * h1.w;
        }
      }
    }
    __syncthreads();
  }
  const size_t rowb = (size_t)n * Kpad;
#pragma unroll
  for (int p = 0; p < NP; p++) {
    int ch = p * 256 + tid;
    if (ch < NCH) {
      u16x8 hv, lv;
#pragma unroll
      for (int j = 0; j < 8; j++) {
        uint16_t hi, lo;
        split_bf(acc[p][j] * scale, hi, lo);
        hv[j] = hi; lv[j] = lo;
      }
      *(u16x8*)(Shi + rowb + ch * 8) = hv;
      *(u16x8*)(Slo + rowb + ch * 8) = lv;
    }
  }
  // root rows = heff[n,:]
  __syncthreads();
  for (int c = tid; c < CIN / 8; c += 256) {
    int i0 = c * 8;
    u16x8 hv, lv;
#pragma unroll
    for (int j = 0; j < 8; j++) {
      int i = i0 + j;
      float raw = Craw[(size_t)n * CIN + i];
      float val = fmaxf(raw * sA[i] + tA[i], 0.f);
      uint16_t hi, lo;
      split_bf(val, hi, lo);
      hv[j] = hi; lv[j] = lo;
    }
    *(u16x8*)(Shi + rowb + K1 + i0) = hv;
    *(u16x8*)(Slo + rowb + K1 + i0) = lv;
  }
}

// scalar variant for CIN=5 (layer 1, reads x directly, no affine)
__global__ __launch_bounds__(256) void build_S5_k(const float* __restrict__ h,
                                                  const float* __restrict__ ea,
                                                  const float* __restrict__ W1,
                                                  const float* __restrict__ b1,
                                                  const int* __restrict__ src,
                                                  const int* __restrict__ csr,
                                                  const int* __restrict__ offsets,
                                                  uint16_t* __restrict__ Shi,
                                                  uint16_t* __restrict__ Slo,
                                                  int Kpad) {
  constexpr int CIN = 5, CH = 8;
  constexpr int K1 = 33 * CIN;   // 165
  constexpr int KT = 34 * CIN;   // 170
  __shared__ float hs[CH][CIN];
  __shared__ float zs[CH][33];
  __shared__ int   es[CH];
  const int n = blockIdx.x;
  const int tid = threadIdx.x;
  const int base = offsets[n];
  const int deg  = offsets[n+1] - base;
  const float scale = 1.f / fmaxf((float)deg, 1.f);
  float acc = 0.f;

  for (int c0 = 0; c0 < deg; c0 += CH) {
    const int cc = min(CH, deg - c0);
    if (tid < cc) es[tid] = csr[base + c0 + tid];
    __syncthreads();
    for (int idx = tid; idx < cc * CIN; idx += 256) {
      int slot = idx / CIN, i = idx - slot * CIN;
      hs[slot][i] = h[(size_t)src[es[slot]] * CIN + i];
    }
    for (int idx = tid; idx < cc * 33; idx += 256) {
      int slot = idx / 33, k = idx - slot * 33;
      float v;
      if (k == 32) v = 1.f;
      else {
        int e = es[slot];
        v = fmaxf(ea[e*3+0] * W1[k] + ea[e*3+1] * W1[32 + k] + ea[e*3+2] * W1[64 + k] + b1[k], 0.f);
      }
      zs[slot][k] = v;
    }
    __syncthreads();
    if (tid < K1) {
      int k = tid / CIN, i = tid - (tid / CIN) * CIN;
      float a = acc;
      for (int c = 0; c < cc; c++) a += zs[c][k] * hs[c][i];
      acc = a;
    }
    __syncthreads();
  }
  const size_t rowb = (size_t)n * Kpad;
  if (tid < K1) {
    uint16_t hi, lo;
    split_bf(acc * scale, hi, lo);
    Shi[rowb + tid] = hi;
    Slo[rowb + tid] = lo;
  }
  if (tid < CIN) {
    uint16_t hi, lo;
    split_bf(h[(size_t)n * CIN + tid], hi, lo);
    Shi[rowb + K1 + tid] = hi;
    Slo[rowb + K1 + tid] = lo;
  }
  for (int ki = KT + tid; ki < Kpad; ki += 256) {
    Shi[rowb + ki] = 0;
    Slo[rowb + ki] = 0;
  }
}

// ---------------- MFMA bf16x3 GEMM: 128x128 tile, 8 waves x (64x32), atomic split-K ----------------
// C (fp32, zero-initialized) accumulates raw S@W2p via atomicAdd. XOR-swizzled LDS: 0 conflicts.
__global__ __launch_bounds__(512, 4) void mfma_gemm_at_k(const uint16_t* __restrict__ Ahi,
                                                         const uint16_t* __restrict__ Alo,
                                                         const uint16_t* __restrict__ Bhi,
                                                         const uint16_t* __restrict__ Blo,
                                                         float* __restrict__ C,
                                                         int Kpad, int Ncol,
                                                         int iters, int SK) {
  __shared__ uint16_t As[2][128][64];   // 32 KB
  __shared__ uint16_t Bs[2][128][64];   // 32 KB
  const int m0 = blockIdx.x * 128, n0 = blockIdx.y * 128;
  const int z  = blockIdx.z;
  const int ibase = iters / SK, irem = iters % SK;
  const int i0    = z * ibase + min(z, irem);
  const int niter = ibase + (z < irem ? 1 : 0);
  const int tid  = threadIdx.x;
  const int lane = tid & 63;
  const int wave = tid >> 6;           // 0..7
  const int wm = wave & 1;             // m half (64)
  const int wn = wave >> 1;            // n quarter (32)
  const int q  = lane >> 4;
  const int mr = lane & 15;

  f32x4 acc[4][2];
#pragma unroll
  for (int a = 0; a < 4; a++)
#pragma unroll
    for (int b = 0; b < 2; b++) acc[a][b] = (f32x4)0.f;

  for (int it = 0; it < niter; it++) {
    const int k0 = (i0 + it) * 64;
    // stage 64 KB: 4096 16B-chunks, 8 per thread
#pragma unroll
    for (int i = 0; i < 8; i++) {
      int chunk = i * 512 + tid;
      int coct = chunk & 7;
      int row  = (chunk >> 3) & 127;
      int plane = (chunk >> 10) & 1;
      int arr   = chunk >> 11;
      const uint16_t* gsrc = arr ? (plane ? Blo : Bhi) : (plane ? Alo : Ahi);
      int grow = (arr ? n0 : m0) + row;
      uint4 v = {0u, 0u, 0u, 0u};
      if (arr == 0 || grow < Ncol)
        v = *(const uint4*)(gsrc + (size_t)grow * Kpad + k0 + coct * 8);
      int soct = coct ^ (row & 7);
      uint16_t* ldst = arr ? &Bs[plane][row][soct * 8] : &As[plane][row][soct * 8];
      *(uint4*)ldst = v;
    }
    __syncthreads();
#pragma unroll
    for (int ks = 0; ks < 2; ks++) {
      const int oct = (ks * 4 + q) ^ (mr & 7);
      bf16x8 bh[2], bl[2];
#pragma unroll
      for (int fn = 0; fn < 2; fn++) {
        int row = wn * 32 + fn * 16 + mr;
        bh[fn] = *(const bf16x8*)&Bs[0][row][oct * 8];
        bl[fn] = *(const bf16x8*)&Bs[1][row][oct * 8];
      }
#pragma unroll
      for (int fm = 0; fm < 4; fm++) {
        int row = wm * 64 + fm * 16 + mr;
        bf16x8 ah = *(const bf16x8*)&As[0][row][oct * 8];
        bf16x8 al = *(const bf16x8*)&As[1][row][oct * 8];
#pragma unroll
        for (int fn = 0; fn < 2; fn++) {
          acc[fm][fn] = __builtin_amdgcn_mfma_f32_16x16x32_bf16(ah, bh[fn], acc[fm][fn], 0, 0, 0);
          acc[fm][fn] = __builtin_amdgcn_mfma_f32_16x16x32_bf16(ah, bl[fn], acc[fm][fn], 0, 0, 0);
          acc[fm][fn] = __builtin_amdgcn_mfma_f32_16x16x32_bf16(al, bh[fn], acc[fm][fn], 0, 0, 0);
        }
      }
    }
    __syncthreads();
  }

  // atomic split-K epilogue; C/D layout: row = q*4 + reg, col = mr (verified)
#pragma unroll
  for (int fm = 0; fm < 4; fm++) {
#pragma unroll
    for (int reg = 0; reg < 4; reg++) {
      int row = m0 + wm * 64 + fm * 16 + q * 4 + reg;
#pragma unroll
      for (int fn = 0; fn < 2; fn++) {
        int col = n0 + wn * 32 + fn * 16 + mr;
        if (col < Ncol)
          atomicAdd(&C[(size_t)row * Ncol + col], acc[fm][fn][reg]);
      }
    }
  }
}

// ---------------- fused affine+ReLU + pool (sorted batch_seg) + final MLP + LeakyReLU ----------------
__global__ __launch_bounds__(256) void pool_final_k(const float* __restrict__ Craw,
                                                    const float* __restrict__ pbias,
                                                    const float* __restrict__ pg,
                                                    const float* __restrict__ pb,
                                                    const float* __restrict__ pm,
                                                    const float* __restrict__ pv,
                                                    const int* __restrict__ seg,
                                                    const float* __restrict__ W,
                                                    const float* __restrict__ b,
                                                    float* __restrict__ out,
                                                    int N, int T) {
  __shared__ float pooled[256];
  const int g = blockIdx.x, tid = threadIdx.x;
  float s3 = pg[tid] * rsqrtf(pv[tid] + BN_EPS);
  float t3 = (pbias[tid] - pm[tid]) * s3 + pb[tid];
  int lo = 0, hi = N;
  while (lo < hi) { int mid = (lo + hi) >> 1; if (seg[mid] < g) lo = mid + 1; else hi = mid; }
  int lo2 = lo, hi2 = N;
  while (lo2 < hi2) { int mid = (lo2 + hi2) >> 1; if (seg[mid] < g + 1) lo2 = mid + 1; else hi2 = mid; }
  const int cnt = lo2 - lo;
  const float inv = 1.f / fmaxf((float)cnt, 1.f);
  float s = 0.f;
  for (int n = lo; n < lo2; n++)
    s += fmaxf(Craw[(size_t)n * 256 + tid] * s3 + t3, 0.f);
  pooled[tid] = s * inv;
  __syncthreads();
  if (tid < T) {
    float acc = b[tid];
    for (int o = 0; o < 256; o++) acc += pooled[o] * W[(size_t)o * T + tid];
    out[(size_t)g * T + tid] = (acc > 0.f) ? acc : 0.1f * acc;
  }
}

// ---------------- host orchestration ----------------
extern "C" void kernel_launch(void* const* d_in, const int* in_sizes, int n_in,
                              void* d_out, int out_size, void* d_ws, size_t ws_size,
                              hipStream_t stream) {
  const float* x   = (const float*)d_in[0];
  const int*   ei  = (const int*)d_in[1];
  const float* ea  = (const float*)d_in[2];
  const int*   seg = (const int*)d_in[3];

  const int N = in_sizes[0] / 5;       // 4096
  const int E = in_sizes[2] / 3;       // 16384
  const int T = in_sizes[35];          // 100
  const int G = out_size / T;          // 128
  const int* src = ei;
  const int* dst = ei + E;

  const float *W1[3], *b1[3], *W2[3], *b2[3], *root[3], *bias[3];
  const float *bng[3], *bnb[3], *bnm[3], *bnv[3];
  for (int l = 0; l < 3; l++) {
    int base = 4 + l * 10;
    W1[l]   = (const float*)d_in[base + 0];
    b1[l]   = (const float*)d_in[base + 1];
    W2[l]   = (const float*)d_in[base + 2];
    b2[l]   = (const float*)d_in[base + 3];
    root[l] = (const float*)d_in[base + 4];
    bias[l] = (const float*)d_in[base + 5];
    bng[l]  = (const float*)d_in[base + 6];
    bnb[l]  = (const float*)d_in[base + 7];
    bnm[l]  = (const float*)d_in[base + 8];
    bnv[l]  = (const float*)d_in[base + 9];
  }
  const float* mlpW = (const float*)d_in[34];
  const float* mlpb = (const float*)d_in[35];

  char* p = (char*)d_ws;
  auto carve = [&](size_t bytes) -> char* {
    char* r = p;
    p += (bytes + 255) & ~(size_t)255;
    return r;
  };
  // --- zero region (single memsetAsync): cnt, C1, C2, C3 (contiguous, each 256B-aligned) ---
  char*  zbase = p;
  int*   cnt = (int*)carve((size_t)N * 4);
  float* C1  = (float*)carve((size_t)N * 64 * 4);
  float* C2  = (float*)carve((size_t)N * 128 * 4);
  float* C3  = (float*)carve((size_t)N * 256 * 4);
  size_t zbytes = (size_t)(p - zbase);

  int*      offsets = (int*)carve((size_t)(N + 1) * 4);
  int*      cursor  = (int*)carve((size_t)N * 4);
  int*      csr     = (int*)carve((size_t)E * 4);
  uint16_t* W1hi = (uint16_t*)carve((size_t)64 * 192 * 2);
  uint16_t* W1lo = (uint16_t*)carve((size_t)64 * 192 * 2);
  uint16_t* W2hi = (uint16_t*)carve((size_t)128 * 2176 * 2);
  uint16_t* W2lo = (uint16_t*)carve((size_t)128 * 2176 * 2);
  uint16_t* W3hi = (uint16_t*)carve((size_t)256 * 4352 * 2);
  uint16_t* W3lo = (uint16_t*)carve((size_t)256 * 4352 * 2);
  const int KPADMAX = 4352;
  uint16_t* Shi = (uint16_t*)carve((size_t)N * KPADMAX * 2);
  uint16_t* Slo = (uint16_t*)carve((size_t)N * KPADMAX * 2);

  hipMemsetAsync(zbase, 0, zbytes, stream);

  // all-layer weight repack
  {
    int total = 64 * 192 + 128 * 2176 + 256 * 4352;
    build_W2pT_all_k<<<(total + 255) / 256, 256, 0, stream>>>(
        W2[0], b2[0], root[0], W1hi, W1lo,
        W2[1], b2[1], root[1], W2hi, W2lo,
        W2[2], b2[2], root[2], W3hi, W3lo);
  }

  // CSR over dst
  hist_k<<<(E + 255) / 256, 256, 0, stream>>>(dst, cnt, E);
  scan_k<<<1, 1024, 0, stream>>>(cnt, offsets, cursor, N, E);
  scatter_k<<<(E + 255) / 256, 256, 0, stream>>>(dst, cursor, csr, E);

  // ---- layer 1: x (N x 5) -> C1 raw (N x 64) ----
  build_S5_k<<<N, 256, 0, stream>>>(x, ea, W1[0], b1[0], src, csr, offsets, Shi, Slo, 192);
  {
    dim3 grid(N / 128, 1, 3);
    mfma_gemm_at_k<<<grid, 512, 0, stream>>>(Shi, Slo, W1hi, W1lo, C1, 192, 64, 3, 3);
  }
  // ---- layer 2: affine1(C1) (N x 64) -> C2 raw (N x 128) ----
  build_S_vec_k<64><<<N, 256, 0, stream>>>(C1, bias[0], bng[0], bnb[0], bnm[0], bnv[0],
                                           ea, W1[1], b1[1], src, csr, offsets, Shi, Slo, 2176);
  {
    dim3 grid(N / 128, 1, 16);
    mfma_gemm_at_k<<<grid, 512, 0, stream>>>(Shi, Slo, W2hi, W2lo, C2, 2176, 128, 34, 16);
  }
  // ---- layer 3: affine2(C2) (N x 128) -> C3 raw (N x 256) ----
  build_S_vec_k<128><<<N, 256, 0, stream>>>(C2, bias[1], bng[1], bnb[1], bnm[1], bnv[1],
                                            ea, W1[2], b1[2], src, csr, offsets, Shi, Slo, 4352);
  {
    dim3 grid(N / 128, 2, 8);
    mfma_gemm_at_k<<<grid, 512, 0, stream>>>(Shi, Slo, W3hi, W3lo, C3, 4352, 256, 68, 8);
  }

  // ---- pool + final MLP (applies affine3+relu on the fly) ----
  pool_final_k<<<G, 256, 0, stream>>>(C3, bias[2], bng[2], bnb[2], bnm[2], bnv[2],
                                      seg, mlpW, mlpb, (float*)d_out, N, T);
}